// Round 11
// baseline (529.923 us; speedup 1.0000x reference)
//
#include <hip/hip_runtime.h>
#include <cstdint>

#define NHEAD 8
#define D1 64      // H1*C1
#define IN_F 128
#define NEG 0.2f
#define NBINS 256  // loss partial-sum bins

__device__ __forceinline__ void fma4(float4& a, float s, const float4& v)
{
    a.x = fmaf(s, v.x, a.x); a.y = fmaf(s, v.y, a.y);
    a.z = fmaf(s, v.z, a.z); a.w = fmaf(s, v.w, a.w);
}

// ---------------- Kernel A: h1 = feat @ W1, a_src1/a_dst1 dots ----------------
// 64x64 block tile, 4x4 register tile/thread, K in two 64-halves.
__global__ __launch_bounds__(256) void k_gemm1(
    const float* __restrict__ feat,
    const float* __restrict__ W1,
    const float* __restrict__ att_s,
    const float* __restrict__ att_d,
    float* __restrict__ h1, float* __restrict__ a_src, float* __restrict__ a_dst,
    int N)
{
    __shared__ float Wh[64 * 64];   // [kk][c], natural layout, 16 KB
    __shared__ float Fh[64 * 68];   // [r][kk], stride 68, 17.4 KB
    const int tid = threadIdx.x;
    const int tx = tid & 15, ty = tid >> 4;
    const int base = blockIdx.x * 64;
    float4 acc0 = {0,0,0,0}, acc1 = {0,0,0,0}, acc2 = {0,0,0,0}, acc3 = {0,0,0,0};

    for (int p = 0; p < 2; ++p) {
        if (p) __syncthreads();
        for (int i = tid; i < 64 * 64; i += 256)
            Wh[i] = W1[p * 4096 + i];
        for (int i = tid; i < 64 * 64; i += 256) {
            int r = i >> 6, kk = i & 63;
            int n = base + r;
            Fh[r * 68 + kk] = (n < N) ? feat[(size_t)n * IN_F + p * 64 + kk] : 0.f;
        }
        __syncthreads();
        const float* wk = &Wh[4 * tx];
        const float* f0 = &Fh[(4 * ty + 0) * 68];
        const float* f1 = &Fh[(4 * ty + 1) * 68];
        const float* f2 = &Fh[(4 * ty + 2) * 68];
        const float* f3 = &Fh[(4 * ty + 3) * 68];
        #pragma unroll 4
        for (int kk = 0; kk < 64; kk += 4) {
            float4 fa = *(const float4*)&f0[kk];
            float4 fb = *(const float4*)&f1[kk];
            float4 fc = *(const float4*)&f2[kk];
            float4 fd = *(const float4*)&f3[kk];
            float4 w0 = *(const float4*)&wk[(kk + 0) * 64];
            float4 w1 = *(const float4*)&wk[(kk + 1) * 64];
            float4 w2 = *(const float4*)&wk[(kk + 2) * 64];
            float4 w3 = *(const float4*)&wk[(kk + 3) * 64];
            fma4(acc0, fa.x, w0); fma4(acc0, fa.y, w1); fma4(acc0, fa.z, w2); fma4(acc0, fa.w, w3);
            fma4(acc1, fb.x, w0); fma4(acc1, fb.y, w1); fma4(acc1, fb.z, w2); fma4(acc1, fb.w, w3);
            fma4(acc2, fc.x, w0); fma4(acc2, fc.y, w1); fma4(acc2, fc.z, w2); fma4(acc2, fc.w, w3);
            fma4(acc3, fd.x, w0); fma4(acc3, fd.y, w1); fma4(acc3, fd.z, w2); fma4(acc3, fd.w, w3);
        }
    }
    const float4 as4 = *(const float4*)&att_s[4 * tx];
    const float4 ad4 = *(const float4*)&att_d[4 * tx];
    float4 accs[4] = {acc0, acc1, acc2, acc3};
    #pragma unroll
    for (int i = 0; i < 4; ++i) {
        int n = base + 4 * ty + i;
        if (n < N) {
            *(float4*)&h1[(size_t)n * D1 + 4 * tx] = accs[i];
            float ps = accs[i].x * as4.x + accs[i].y * as4.y + accs[i].z * as4.z + accs[i].w * as4.w;
            float pd = accs[i].x * ad4.x + accs[i].y * ad4.y + accs[i].z * ad4.z + accs[i].w * ad4.w;
            ps += __shfl_xor(ps, 1);
            pd += __shfl_xor(pd, 1);
            if ((tx & 1) == 0) {
                a_src[n * NHEAD + (tx >> 1)] = ps;
                a_dst[n * NHEAD + (tx >> 1)] = pd;
            }
        }
    }
}

// ---------------- CSR build: 8-way partitioned histogram ----------------
// Round-10 theory: single deg[] table = cross-XCD L2 line ping-pong on every
// atomic. Partition by p=blockIdx&7 (~XCD under round-robin dispatch): same-p
// blocks share counter copies; fill writes each node's p-segment from same-p
// blocks only.
__global__ __launch_bounds__(256) void k_hist8(
    const int* __restrict__ dst, int* __restrict__ deg8, int* __restrict__ rank,
    int E, int N)
{
    int e = blockIdx.x * 256 + threadIdx.x;
    if (e < E) {
        int p = blockIdx.x & 7;
        rank[e] = atomicAdd(&deg8[p * N + dst[e]], 1);   // rank write coalesced
    }
}

__global__ __launch_bounds__(256) void k_reduce8(
    const int* __restrict__ deg8, int* __restrict__ base8,
    int* __restrict__ deg, int N)
{
    int d = blockIdx.x * 256 + threadIdx.x;
    if (d < N) {
        int b = 0;
        #pragma unroll
        for (int p = 0; p < 8; ++p) {
            base8[p * N + d] = b;
            b += deg8[p * N + d];
        }
        deg[d] = b;
    }
}

__device__ __forceinline__ int block_incl_scan(int v, int tid, int* lds4)
{
    int lane = tid & 63, w = tid >> 6;
    #pragma unroll
    for (int off = 1; off < 64; off <<= 1) {
        int t = __shfl_up(v, off);
        if (lane >= off) v += t;
    }
    if (lane == 63) lds4[w] = v;
    __syncthreads();
    int add = 0;
    #pragma unroll
    for (int i = 0; i < 4; ++i)
        if (i < w) add += lds4[i];
    __syncthreads();
    return v + add;
}

__global__ __launch_bounds__(256) void k_scan1(
    const int* __restrict__ deg, int* __restrict__ locx, int* __restrict__ bsum,
    double* __restrict__ bins, int N)
{
    __shared__ int lds4[4];
    if (blockIdx.x == 0) bins[threadIdx.x] = 0.0;   // fold bins memset here
    int i = blockIdx.x * 256 + threadIdx.x;
    int v = (i < N) ? deg[i] : 0;
    int incl = block_incl_scan(v, threadIdx.x, lds4);
    if (i < N) locx[i] = incl - v;
    if (threadIdx.x == 255) bsum[blockIdx.x] = incl;
}

__global__ __launch_bounds__(256) void k_scan2(int* __restrict__ bsum, int nblk)
{
    __shared__ int lds4[4];
    __shared__ int carry;
    if (threadIdx.x == 0) carry = 0;
    __syncthreads();
    for (int base = 0; base < nblk; base += 256) {
        int i = base + threadIdx.x;
        int v = (i < nblk) ? bsum[i] : 0;
        int incl = block_incl_scan(v, threadIdx.x, lds4);
        int c = carry;
        __syncthreads();
        if (i < nblk) bsum[i] = incl - v + c;
        if (threadIdx.x == 255) carry = c + incl;
        __syncthreads();
    }
}

__global__ __launch_bounds__(256) void k_scan3(
    const int* __restrict__ locx, const int* __restrict__ bsum,
    int* __restrict__ offs, int N)
{
    int i = blockIdx.x * 256 + threadIdx.x;
    if (i < N) offs[i] = locx[i] + bsum[i >> 8];
}

// atomicExch: plain scattered 4B stores write through at 64B/op; exch stays in L2.
__global__ __launch_bounds__(256) void k_fill(
    const int* __restrict__ src, const int* __restrict__ dst,
    const int* __restrict__ rank, const int* __restrict__ offs,
    const int* __restrict__ base8,
    int* __restrict__ srcs, int E, int N)
{
    int e = blockIdx.x * 256 + threadIdx.x;
    if (e < E) {
        int p = blockIdx.x & 7;           // must match k_hist8's p for this e
        int d = dst[e];
        int slot = offs[d] + base8[p * N + d] + rank[e];
        (void)atomicExch(&srcs[slot], src[e]);
    }
}

// ---------------- Layer-1 aggregation (round-9 form: scalar 8-gather) ----------------
__global__ __launch_bounds__(256) void k_agg1(
    const int* __restrict__ deg, const int* __restrict__ offs,
    const int* __restrict__ srcs,
    const float* __restrict__ a_s, const float* __restrict__ a_d,
    const float* __restrict__ h1, const float* __restrict__ b1,
    float* __restrict__ x, int N)
{
    const int tid = threadIdx.x, w = tid >> 6, j = tid & 63;
    const int c = j & 7, hh = j >> 3;      // producer: edge-slot c, head hh
    const int n = blockIdx.x * 4 + w;
    if (n >= N) return;
    const int rlen = deg[n], row = offs[n];
    const float ad = a_d[n * NHEAD + hh];
    float acc0 = 0.f, acc1 = 0.f, den = 0.f;
    for (int base = 0; base < rlen; base += 8) {
        int m = rlen - base; if (m > 8) m = 8;
        int myS = 0; float ex = 0.f;
        if (c < m) {
            myS = srcs[row + base + c];
            float v = a_s[myS * NHEAD + hh] + ad;
            v = v > 0.f ? v : NEG * v;
            ex = expf(v);
        }
        float ds = ex;                      // per-head denom: aligned 8-lane group reduce
        ds += __shfl_xor(ds, 1);
        ds += __shfl_xor(ds, 2);
        ds += __shfl_xor(ds, 4);
        den += ds;
        if (m == 8) {
            int   s8[8]; float e8[8], l8[8];
            #pragma unroll
            for (int k = 0; k < 8; ++k) {
                s8[k] = __builtin_amdgcn_readlane(myS, k);
                e8[k] = __shfl(ex, (j & 0x38) | k);
            }
            #pragma unroll
            for (int k = 0; k < 8; ++k)
                l8[k] = h1[(size_t)s8[k] * D1 + j];   // 8 loads in flight
            #pragma unroll
            for (int k = 0; k < 8; ++k) {
                if (k & 1) acc1 = fmaf(e8[k], l8[k], acc1);
                else       acc0 = fmaf(e8[k], l8[k], acc0);
            }
        } else {
            for (int k = 0; k < m; ++k) {
                int s = __shfl(myS, k);
                float exk = __shfl(ex, (j & 0x38) | k);
                if (k & 1) acc1 = fmaf(exk, h1[(size_t)s * D1 + j], acc1);
                else       acc0 = fmaf(exk, h1[(size_t)s * D1 + j], acc0);
            }
        }
    }
    float o = (acc0 + acc1) / den + b1[j];
    x[(size_t)n * D1 + j] = o > 0.f ? o : expm1f(o);
}

// ---------------- Kernel D: h2 = x @ W2, a_src2/a_dst2 (4x4 register tile) ----------------
__global__ __launch_bounds__(256) void k_gemm2(
    const float* __restrict__ x,
    const float* __restrict__ W2,
    const float* __restrict__ att_s,
    const float* __restrict__ att_d,
    float* __restrict__ h2, float* __restrict__ a_src, float* __restrict__ a_dst,
    int N)
{
    __shared__ float Wh[64 * 64];
    __shared__ float Fh[64 * 68];
    const int tid = threadIdx.x;
    const int tx = tid & 15, ty = tid >> 4;
    const int base = blockIdx.x * 64;
    for (int i = tid; i < 64 * 64; i += 256)
        Wh[i] = W2[i];
    for (int i = tid; i < 64 * 64; i += 256) {
        int r = i >> 6, kk = i & 63;
        int n = base + r;
        Fh[r * 68 + kk] = (n < N) ? x[(size_t)n * 64 + kk] : 0.f;
    }
    __syncthreads();
    float4 acc0 = {0,0,0,0}, acc1 = {0,0,0,0}, acc2 = {0,0,0,0}, acc3 = {0,0,0,0};
    const float* wk = &Wh[4 * tx];
    const float* f0 = &Fh[(4 * ty + 0) * 68];
    const float* f1 = &Fh[(4 * ty + 1) * 68];
    const float* f2 = &Fh[(4 * ty + 2) * 68];
    const float* f3 = &Fh[(4 * ty + 3) * 68];
    #pragma unroll 4
    for (int kk = 0; kk < 64; kk += 4) {
        float4 fa = *(const float4*)&f0[kk];
        float4 fb = *(const float4*)&f1[kk];
        float4 fc = *(const float4*)&f2[kk];
        float4 fd = *(const float4*)&f3[kk];
        float4 w0 = *(const float4*)&wk[(kk + 0) * 64];
        float4 w1 = *(const float4*)&wk[(kk + 1) * 64];
        float4 w2 = *(const float4*)&wk[(kk + 2) * 64];
        float4 w3 = *(const float4*)&wk[(kk + 3) * 64];
        fma4(acc0, fa.x, w0); fma4(acc0, fa.y, w1); fma4(acc0, fa.z, w2); fma4(acc0, fa.w, w3);
        fma4(acc1, fb.x, w0); fma4(acc1, fb.y, w1); fma4(acc1, fb.z, w2); fma4(acc1, fb.w, w3);
        fma4(acc2, fc.x, w0); fma4(acc2, fc.y, w1); fma4(acc2, fc.z, w2); fma4(acc2, fc.w, w3);
        fma4(acc3, fd.x, w0); fma4(acc3, fd.y, w1); fma4(acc3, fd.z, w2); fma4(acc3, fd.w, w3);
    }
    const float4 as4 = *(const float4*)&att_s[4 * tx];
    const float4 ad4 = *(const float4*)&att_d[4 * tx];
    float4 accs[4] = {acc0, acc1, acc2, acc3};
    #pragma unroll
    for (int i = 0; i < 4; ++i) {
        int n = base + 4 * ty + i;
        if (n < N) {
            *(float4*)&h2[(size_t)n * 64 + 4 * tx] = accs[i];
            float ps = accs[i].x * as4.x + accs[i].y * as4.y + accs[i].z * as4.z + accs[i].w * as4.w;
            float pd = accs[i].x * ad4.x + accs[i].y * ad4.y + accs[i].z * ad4.z + accs[i].w * ad4.w;
            ps += __shfl_xor(ps, 1); pd += __shfl_xor(pd, 1);
            ps += __shfl_xor(ps, 2); pd += __shfl_xor(pd, 2);
            ps += __shfl_xor(ps, 4); pd += __shfl_xor(pd, 4);
            ps += __shfl_xor(ps, 8); pd += __shfl_xor(pd, 8);
            if (tx == 0) { a_src[n] = ps; a_dst[n] = pd; }
        }
    }
}

// ---------------- Layer-2 aggregation + bias + log-softmax + argmax + NLL ----------------
// float4 consumer (channels 4t..4t+3, edge subset q mod 4), 16-edge unrolled groups.
__global__ __launch_bounds__(256) void k_agg2(
    const int* __restrict__ deg, const int* __restrict__ offs,
    const int* __restrict__ srcs,
    const float* __restrict__ a_s, const float* __restrict__ a_d,
    const float* __restrict__ h2, const float* __restrict__ b2,
    const int* __restrict__ label,
    float* __restrict__ dout, double* __restrict__ bins, int N)
{
    __shared__ float snll[4];
    const int tid = threadIdx.x, w = tid >> 6, j = tid & 63;
    const int t = j & 15, q = j >> 4;
    const int n = blockIdx.x * 4 + w;
    if (j == 0) snll[w] = 0.f;
    if (n < N) {
        const int rlen = deg[n], row = offs[n];
        const float ad = a_d[n];
        float4 acc = {0.f, 0.f, 0.f, 0.f};
        float den = 0.f;
        for (int base = 0; base < rlen; base += 64) {
            int m = rlen - base; if (m > 64) m = 64;
            int myS = 0; float ex = 0.f;
            if (j < m) {
                myS = srcs[row + base + j];
                float v = a_s[myS] + ad;
                v = v > 0.f ? v : NEG * v;
                ex = expf(v);
            }
            float ds = ex;
            #pragma unroll
            for (int off = 1; off < 64; off <<= 1) ds += __shfl_xor(ds, off);
            den += ds;
            int eb = 0;
            for (; eb + 16 <= m; eb += 16) {           // 4 gathers in flight
                int s4[4]; float e4[4]; float4 l4[4];
                #pragma unroll
                for (int ii = 0; ii < 4; ++ii) {
                    int e = eb + 4 * ii + q;
                    s4[ii] = __shfl(myS, e);
                    e4[ii] = __shfl(ex, e);
                }
                #pragma unroll
                for (int ii = 0; ii < 4; ++ii)
                    l4[ii] = *(const float4*)&h2[(size_t)s4[ii] * 64 + 4 * t];
                #pragma unroll
                for (int ii = 0; ii < 4; ++ii)
                    fma4(acc, e4[ii], l4[ii]);
            }
            for (; eb + 4 <= m; eb += 4) {
                int e = eb + q;
                int sk = __shfl(myS, e);
                float ek = __shfl(ex, e);
                float4 lk = *(const float4*)&h2[(size_t)sk * 64 + 4 * t];
                fma4(acc, ek, lk);
            }
            for (int k = eb; k < m; ++k) {
                int sk = __shfl(myS, k);
                float ek = __shfl(ex, k);
                if (q == (k & 3)) {
                    float4 lk = *(const float4*)&h2[(size_t)sk * 64 + 4 * t];
                    fma4(acc, ek, lk);
                }
            }
        }
        acc.x += __shfl_xor(acc.x, 16); acc.y += __shfl_xor(acc.y, 16);
        acc.z += __shfl_xor(acc.z, 16); acc.w += __shfl_xor(acc.w, 16);
        acc.x += __shfl_xor(acc.x, 32); acc.y += __shfl_xor(acc.y, 32);
        acc.z += __shfl_xor(acc.z, 32); acc.w += __shfl_xor(acc.w, 32);
        float4 b = *(const float4*)&b2[4 * t];
        float4 sc;
        sc.x = acc.x / den + b.x; sc.y = acc.y / den + b.y;
        sc.z = acc.z / den + b.z; sc.w = acc.w / den + b.w;
        float mv = sc.x; int mi = 4 * t;
        if (sc.y > mv) { mv = sc.y; mi = 4 * t + 1; }
        if (sc.z > mv) { mv = sc.z; mi = 4 * t + 2; }
        if (sc.w > mv) { mv = sc.w; mi = 4 * t + 3; }
        #pragma unroll
        for (int off = 1; off < 16; off <<= 1) {
            float ov = __shfl_xor(mv, off);
            int oi = __shfl_xor(mi, off);
            if (ov > mv || (ov == mv && oi < mi)) { mv = ov; mi = oi; }
        }
        float se = expf(sc.x - mv) + expf(sc.y - mv) + expf(sc.z - mv) + expf(sc.w - mv);
        #pragma unroll
        for (int off = 1; off < 16; off <<= 1) se += __shfl_xor(se, off);
        int lab = label[n];
        int comp = lab & 3;
        float cl = comp == 0 ? sc.x : comp == 1 ? sc.y : comp == 2 ? sc.z : sc.w;
        float sl = __shfl(cl, (j & 0x30) | (lab >> 2));
        if (j == 0) {
            snll[w] = mv + logf(se) - sl;
            dout[1 + n] = (float)mi;
            dout[1 + (size_t)N + n] = (float)lab;
        }
    }
    __syncthreads();
    if (tid == 0) {
        double bsum = (double)snll[0] + (double)snll[1]
                    + (double)snll[2] + (double)snll[3];
        atomicAdd(&bins[blockIdx.x & (NBINS - 1)], bsum);
    }
}

// Single block of 256: reduce NBINS doubles -> loss
__global__ __launch_bounds__(256) void k_loss(
    const double* __restrict__ bins, float* __restrict__ dout, int N)
{
    __shared__ double sw[4];
    const int tid = threadIdx.x;
    double v = bins[tid];
    #pragma unroll
    for (int off = 1; off < 64; off <<= 1) v += __shfl_xor(v, off);
    if ((tid & 63) == 0) sw[tid >> 6] = v;
    __syncthreads();
    if (tid == 0)
        dout[0] = (float)((sw[0] + sw[1] + sw[2] + sw[3]) / (double)N);
}

extern "C" void kernel_launch(void* const* d_in, const int* in_sizes, int n_in,
                              void* d_out, int out_size, void* d_ws, size_t ws_size,
                              hipStream_t stream)
{
    const float* feat   = (const float*)d_in[1];
    const int*   edge   = (const int*)d_in[2];
    const int*   label  = (const int*)d_in[4];
    const float* W1     = (const float*)d_in[5];
    const float* att_s1 = (const float*)d_in[6];
    const float* att_d1 = (const float*)d_in[7];
    const float* b1     = (const float*)d_in[8];
    const float* W2     = (const float*)d_in[9];
    const float* att_s2 = (const float*)d_in[10];
    const float* att_d2 = (const float*)d_in[11];
    const float* b2     = (const float*)d_in[12];

    const int N = in_sizes[0];
    const int E = in_sizes[2] / 2;
    const int* src = edge;
    const int* dst = edge + E;

    // workspace layout (~66 MB):
    float* bufA = (float*)d_ws;               // N*64: h1/h2; ALSO aliases deg8[8N]+base8[8N]
    float* bufB = bufA + (size_t)N * 64;      // N*64: x; ALSO aliases rank[E]
    float* a_s1 = bufB + (size_t)N * 64;      // N*8 (layer2: a_s2=[0..N), a_d2=[N..2N))
    float* a_d1 = a_s1 + (size_t)N * 8;       // N*8
    int*   deg  = (int*)(a_d1 + (size_t)N * 8); // N
    int*   offs = deg + N;                    // N
    int*   srcs = offs + N;                   // E
    int*   locx = srcs + E;                   // N (scan scratch)
    int*   bsum = locx + N;                   // nblk (scan scratch)
    double* bins = (double*)(((uintptr_t)(bsum + ((N + 255) / 256) + 1) + 7) & ~(uintptr_t)7);

    // Aliases (all dead before their underlying buffer is first written):
    // deg8/base8 in bufA (gemm1 writes bufA after k_fill); rank in bufB (agg1
    // writes bufB after k_fill). 16N ints << 64N floats; E <= 64N.
    int* deg8  = (int*)bufA;                  // 8N
    int* base8 = deg8 + (size_t)8 * N;        // 8N
    int* rank  = (int*)bufB;                  // E

    float* a_s2 = a_s1;
    float* a_d2 = a_s1 + N;

    float* out = (float*)d_out;

    const int nblk = (N + 255) / 256;
    const int egrid = (E + 255) / 256;

    hipMemsetAsync(deg8, 0, (size_t)8 * N * sizeof(int), stream);

    // CSR build (rebuilt every call — no static state)
    k_hist8 <<<egrid, 256, 0, stream>>>(dst, deg8, rank, E, N);
    k_reduce8<<<nblk, 256, 0, stream>>>(deg8, base8, deg, N);
    k_scan1 <<<nblk, 256, 0, stream>>>(deg, locx, bsum, bins, N);
    k_scan2 <<<1, 256, 0, stream>>>(bsum, nblk);
    k_scan3 <<<nblk, 256, 0, stream>>>(locx, bsum, offs, N);
    k_fill  <<<egrid, 256, 0, stream>>>(src, dst, rank, offs, base8, srcs, E, N);

    k_gemm1<<<(N + 63) / 64, 256, 0, stream>>>(feat, W1, att_s1, att_d1, bufA, a_s1, a_d1, N);
    k_agg1 <<<(N + 3) / 4, 256, 0, stream>>>(deg, offs, srcs, a_s1, a_d1, bufA, b1, bufB, N);
    k_gemm2<<<(N + 63) / 64, 256, 0, stream>>>(bufB, W2, att_s2, att_d2, bufA, a_s2, a_d2, N);
    k_agg2 <<<(N + 3) / 4, 256, 0, stream>>>(deg, offs, srcs, a_s2, a_d2, bufA, b2, label,
                                             out, bins, N);
    k_loss <<<1, 256, 0, stream>>>(bins, out, N);
}

// Round 12
// 510.211 us; speedup vs baseline: 1.0386x; 1.0386x over previous
//
#include <hip/hip_runtime.h>
#include <cstdint>

#define NHEAD 8
#define D1 64      // H1*C1
#define IN_F 128
#define NEG 0.2f
#define NBINS 256  // loss partial-sum bins

__device__ __forceinline__ void fma4(float4& a, float s, const float4& v)
{
    a.x = fmaf(s, v.x, a.x); a.y = fmaf(s, v.y, a.y);
    a.z = fmaf(s, v.z, a.z); a.w = fmaf(s, v.w, a.w);
}

// ---------------- Fused: gemm1 (h1 = feat@W1 + att dots) & hist8 ----------------
// Round-11 lesson: gemm1 and the CSR histogram are independent — overlap them in
// one dispatch instead of serializing. Blocks [0,G1) do gemm1; the rest do hist.
__global__ __launch_bounds__(256) void k_gemm1_hist(
    const float* __restrict__ feat,
    const float* __restrict__ W1,
    const float* __restrict__ att_s,
    const float* __restrict__ att_d,
    float* __restrict__ h1, float* __restrict__ a_src, float* __restrict__ a_dst,
    const int* __restrict__ dst, int* __restrict__ deg8, int* __restrict__ rank,
    int N, int E, int G1)
{
    __shared__ float Wh[64 * 64];   // [kk][c], 16 KB
    __shared__ float Fh[64 * 68];   // [r][kk], stride 68, 17.4 KB
    const int tid = threadIdx.x;

    if ((int)blockIdx.x >= G1) {
        // -------- histogram branch (8-way partitioned by block; p=(e>>8)&7) -----
        int bid = blockIdx.x - G1;
        int e = bid * 256 + tid;
        if (e < E) {
            int p = bid & 7;
            rank[e] = atomicAdd(&deg8[p * N + dst[e]], 1);  // rank write coalesced
        }
        return;
    }

    // -------- gemm1 branch: 64x64 tile, 4x4 register tile, K in two halves -----
    const int tx = tid & 15, ty = tid >> 4;
    const int base = blockIdx.x * 64;
    float4 acc0 = {0,0,0,0}, acc1 = {0,0,0,0}, acc2 = {0,0,0,0}, acc3 = {0,0,0,0};

    for (int p = 0; p < 2; ++p) {
        if (p) __syncthreads();
        for (int i = tid; i < 64 * 64; i += 256)
            Wh[i] = W1[p * 4096 + i];
        for (int i = tid; i < 64 * 64; i += 256) {
            int r = i >> 6, kk = i & 63;
            int n = base + r;
            Fh[r * 68 + kk] = (n < N) ? feat[(size_t)n * IN_F + p * 64 + kk] : 0.f;
        }
        __syncthreads();
        const float* wk = &Wh[4 * tx];
        const float* f0 = &Fh[(4 * ty + 0) * 68];
        const float* f1 = &Fh[(4 * ty + 1) * 68];
        const float* f2 = &Fh[(4 * ty + 2) * 68];
        const float* f3 = &Fh[(4 * ty + 3) * 68];
        #pragma unroll 4
        for (int kk = 0; kk < 64; kk += 4) {
            float4 fa = *(const float4*)&f0[kk];
            float4 fb = *(const float4*)&f1[kk];
            float4 fc = *(const float4*)&f2[kk];
            float4 fd = *(const float4*)&f3[kk];
            float4 w0 = *(const float4*)&wk[(kk + 0) * 64];
            float4 w1 = *(const float4*)&wk[(kk + 1) * 64];
            float4 w2 = *(const float4*)&wk[(kk + 2) * 64];
            float4 w3 = *(const float4*)&wk[(kk + 3) * 64];
            fma4(acc0, fa.x, w0); fma4(acc0, fa.y, w1); fma4(acc0, fa.z, w2); fma4(acc0, fa.w, w3);
            fma4(acc1, fb.x, w0); fma4(acc1, fb.y, w1); fma4(acc1, fb.z, w2); fma4(acc1, fb.w, w3);
            fma4(acc2, fc.x, w0); fma4(acc2, fc.y, w1); fma4(acc2, fc.z, w2); fma4(acc2, fc.w, w3);
            fma4(acc3, fd.x, w0); fma4(acc3, fd.y, w1); fma4(acc3, fd.z, w2); fma4(acc3, fd.w, w3);
        }
    }
    const float4 as4 = *(const float4*)&att_s[4 * tx];
    const float4 ad4 = *(const float4*)&att_d[4 * tx];
    float4 accs[4] = {acc0, acc1, acc2, acc3};
    #pragma unroll
    for (int i = 0; i < 4; ++i) {
        int n = base + 4 * ty + i;
        if (n < N) {
            *(float4*)&h1[(size_t)n * D1 + 4 * tx] = accs[i];
            float ps = accs[i].x * as4.x + accs[i].y * as4.y + accs[i].z * as4.z + accs[i].w * as4.w;
            float pd = accs[i].x * ad4.x + accs[i].y * ad4.y + accs[i].z * ad4.z + accs[i].w * ad4.w;
            ps += __shfl_xor(ps, 1);
            pd += __shfl_xor(pd, 1);
            if ((tx & 1) == 0) {
                a_src[n * NHEAD + (tx >> 1)] = ps;
                a_dst[n * NHEAD + (tx >> 1)] = pd;
            }
        }
    }
}

__device__ __forceinline__ int block_incl_scan(int v, int tid, int* lds4)
{
    int lane = tid & 63, w = tid >> 6;
    #pragma unroll
    for (int off = 1; off < 64; off <<= 1) {
        int t = __shfl_up(v, off);
        if (lane >= off) v += t;
    }
    if (lane == 63) lds4[w] = v;
    __syncthreads();
    int add = 0;
    #pragma unroll
    for (int i = 0; i < 4; ++i)
        if (i < w) add += lds4[i];
    __syncthreads();
    return v + add;
}

// scan1 with reduce8 folded in: deg = sum_p deg8, base8 = per-p exclusive bases.
__global__ __launch_bounds__(256) void k_scan1r(
    const int* __restrict__ deg8, int* __restrict__ base8, int* __restrict__ deg,
    int* __restrict__ locx, int* __restrict__ bsum, double* __restrict__ bins, int N)
{
    __shared__ int lds4[4];
    if (blockIdx.x == 0) bins[threadIdx.x] = 0.0;   // fold bins zeroing here
    int i = blockIdx.x * 256 + threadIdx.x;
    int v = 0;
    if (i < N) {
        int b = 0;
        #pragma unroll
        for (int p = 0; p < 8; ++p) {
            base8[p * N + i] = b;
            b += deg8[p * N + i];
        }
        deg[i] = b;
        v = b;
    }
    int incl = block_incl_scan(v, threadIdx.x, lds4);
    if (i < N) locx[i] = incl - v;
    if (threadIdx.x == 255) bsum[blockIdx.x] = incl;
}

__global__ __launch_bounds__(256) void k_scan2(int* __restrict__ bsum, int nblk)
{
    __shared__ int lds4[4];
    __shared__ int carry;
    if (threadIdx.x == 0) carry = 0;
    __syncthreads();
    for (int base = 0; base < nblk; base += 256) {
        int i = base + threadIdx.x;
        int v = (i < nblk) ? bsum[i] : 0;
        int incl = block_incl_scan(v, threadIdx.x, lds4);
        int c = carry;
        __syncthreads();
        if (i < nblk) bsum[i] = incl - v + c;
        if (threadIdx.x == 255) carry = c + incl;
        __syncthreads();
    }
}

// scan3 deleted: consumers compute offs = locx[d] + bsum[d>>8] (both L2-hot).
// atomicExch: plain scattered 4B stores write through at 64B/op; exch stays in L2.
__global__ __launch_bounds__(256) void k_fill(
    const int* __restrict__ src, const int* __restrict__ dst,
    const int* __restrict__ rank, const int* __restrict__ locx,
    const int* __restrict__ bsum, const int* __restrict__ base8,
    int* __restrict__ srcs, int E, int N)
{
    int e = blockIdx.x * 256 + threadIdx.x;
    if (e < E) {
        int p = blockIdx.x & 7;           // matches hist branch's p=(e>>8)&7
        int d = dst[e];
        int slot = locx[d] + bsum[d >> 8] + base8[p * N + d] + rank[e];
        (void)atomicExch(&srcs[slot], src[e]);
    }
}

// ---------------- Layer-1 aggregation, 2-deep software pipeline ----------------
// Round-11 theory: per-chunk chain srcs->a_s->gathers = 3 serial latencies.
// Prefetch next chunk's srcs AND a_s at loop head; they fly while the current
// chunk's 8 gathers drain.
__global__ __launch_bounds__(256) void k_agg1(
    const int* __restrict__ deg, const int* __restrict__ locx,
    const int* __restrict__ bsum, const int* __restrict__ srcs,
    const float* __restrict__ a_s, const float* __restrict__ a_d,
    const float* __restrict__ h1, const float* __restrict__ b1,
    float* __restrict__ x, int N)
{
    const int tid = threadIdx.x, w = tid >> 6, j = tid & 63;
    const int c = j & 7, hh = j >> 3;      // producer: edge-slot c, head hh
    const int n = blockIdx.x * 4 + w;
    if (n >= N) return;
    const int rlen = deg[n];
    const int row = locx[n] + bsum[n >> 8];
    const float ad = a_d[n * NHEAD + hh];
    float acc0 = 0.f, acc1 = 0.f, den = 0.f;
    int m = rlen < 8 ? rlen : 8;
    int myS   = (c < m) ? srcs[row + c] : 0;
    float av  = (c < m) ? a_s[myS * NHEAD + hh] : 0.f;
    for (int base = 0; base < rlen; base += 8) {
        int mn = rlen - base - 8; if (mn > 8) mn = 8;
        int   myS_n = (c < mn) ? srcs[row + base + 8 + c] : 0;
        float av_n  = (c < mn) ? a_s[myS_n * NHEAD + hh] : 0.f;
        float ex = 0.f;
        if (c < m) {
            float v = av + ad;
            v = v > 0.f ? v : NEG * v;
            ex = expf(v);
        }
        float ds = ex;                      // per-head denom: aligned 8-lane group reduce
        ds += __shfl_xor(ds, 1);
        ds += __shfl_xor(ds, 2);
        ds += __shfl_xor(ds, 4);
        den += ds;
        if (m == 8) {
            int   s8[8]; float e8[8], l8[8];
            #pragma unroll
            for (int k = 0; k < 8; ++k) {
                s8[k] = __builtin_amdgcn_readlane(myS, k);
                e8[k] = __shfl(ex, (j & 0x38) | k);
            }
            #pragma unroll
            for (int k = 0; k < 8; ++k)
                l8[k] = h1[(size_t)s8[k] * D1 + j];   // 8 loads in flight
            #pragma unroll
            for (int k = 0; k < 8; ++k) {
                if (k & 1) acc1 = fmaf(e8[k], l8[k], acc1);
                else       acc0 = fmaf(e8[k], l8[k], acc0);
            }
        } else {
            for (int k = 0; k < m; ++k) {
                int s = __shfl(myS, k);
                float exk = __shfl(ex, (j & 0x38) | k);
                if (k & 1) acc1 = fmaf(exk, h1[(size_t)s * D1 + j], acc1);
                else       acc0 = fmaf(exk, h1[(size_t)s * D1 + j], acc0);
            }
        }
        myS = myS_n; av = av_n; m = mn > 0 ? mn : 0;
    }
    float o = (acc0 + acc1) / den + b1[j];
    x[(size_t)n * D1 + j] = o > 0.f ? o : expm1f(o);
}

// ---------------- Kernel D: h2 = x @ W2, a_src2/a_dst2 (4x4 register tile) ----------------
__global__ __launch_bounds__(256) void k_gemm2(
    const float* __restrict__ x,
    const float* __restrict__ W2,
    const float* __restrict__ att_s,
    const float* __restrict__ att_d,
    float* __restrict__ h2, float* __restrict__ a_src, float* __restrict__ a_dst,
    int N)
{
    __shared__ float Wh[64 * 64];
    __shared__ float Fh[64 * 68];
    const int tid = threadIdx.x;
    const int tx = tid & 15, ty = tid >> 4;
    const int base = blockIdx.x * 64;
    for (int i = tid; i < 64 * 64; i += 256)
        Wh[i] = W2[i];
    for (int i = tid; i < 64 * 64; i += 256) {
        int r = i >> 6, kk = i & 63;
        int n = base + r;
        Fh[r * 68 + kk] = (n < N) ? x[(size_t)n * 64 + kk] : 0.f;
    }
    __syncthreads();
    float4 acc0 = {0,0,0,0}, acc1 = {0,0,0,0}, acc2 = {0,0,0,0}, acc3 = {0,0,0,0};
    const float* wk = &Wh[4 * tx];
    const float* f0 = &Fh[(4 * ty + 0) * 68];
    const float* f1 = &Fh[(4 * ty + 1) * 68];
    const float* f2 = &Fh[(4 * ty + 2) * 68];
    const float* f3 = &Fh[(4 * ty + 3) * 68];
    #pragma unroll 4
    for (int kk = 0; kk < 64; kk += 4) {
        float4 fa = *(const float4*)&f0[kk];
        float4 fb = *(const float4*)&f1[kk];
        float4 fc = *(const float4*)&f2[kk];
        float4 fd = *(const float4*)&f3[kk];
        float4 w0 = *(const float4*)&wk[(kk + 0) * 64];
        float4 w1 = *(const float4*)&wk[(kk + 1) * 64];
        float4 w2 = *(const float4*)&wk[(kk + 2) * 64];
        float4 w3 = *(const float4*)&wk[(kk + 3) * 64];
        fma4(acc0, fa.x, w0); fma4(acc0, fa.y, w1); fma4(acc0, fa.z, w2); fma4(acc0, fa.w, w3);
        fma4(acc1, fb.x, w0); fma4(acc1, fb.y, w1); fma4(acc1, fb.z, w2); fma4(acc1, fb.w, w3);
        fma4(acc2, fc.x, w0); fma4(acc2, fc.y, w1); fma4(acc2, fc.z, w2); fma4(acc2, fc.w, w3);
        fma4(acc3, fd.x, w0); fma4(acc3, fd.y, w1); fma4(acc3, fd.z, w2); fma4(acc3, fd.w, w3);
    }
    const float4 as4 = *(const float4*)&att_s[4 * tx];
    const float4 ad4 = *(const float4*)&att_d[4 * tx];
    float4 accs[4] = {acc0, acc1, acc2, acc3};
    #pragma unroll
    for (int i = 0; i < 4; ++i) {
        int n = base + 4 * ty + i;
        if (n < N) {
            *(float4*)&h2[(size_t)n * 64 + 4 * tx] = accs[i];
            float ps = accs[i].x * as4.x + accs[i].y * as4.y + accs[i].z * as4.z + accs[i].w * as4.w;
            float pd = accs[i].x * ad4.x + accs[i].y * ad4.y + accs[i].z * ad4.z + accs[i].w * ad4.w;
            ps += __shfl_xor(ps, 1); pd += __shfl_xor(pd, 1);
            ps += __shfl_xor(ps, 2); pd += __shfl_xor(pd, 2);
            ps += __shfl_xor(ps, 4); pd += __shfl_xor(pd, 4);
            ps += __shfl_xor(ps, 8); pd += __shfl_xor(pd, 8);
            if (tx == 0) { a_src[n] = ps; a_dst[n] = pd; }
        }
    }
}

// ---------------- Layer-2 aggregation + bias + log-softmax + argmax + NLL ----------------
__global__ __launch_bounds__(256) void k_agg2(
    const int* __restrict__ deg, const int* __restrict__ locx,
    const int* __restrict__ bsum, const int* __restrict__ srcs,
    const float* __restrict__ a_s, const float* __restrict__ a_d,
    const float* __restrict__ h2, const float* __restrict__ b2,
    const int* __restrict__ label,
    float* __restrict__ dout, double* __restrict__ bins, int N)
{
    __shared__ float snll[4];
    const int tid = threadIdx.x, w = tid >> 6, j = tid & 63;
    const int t = j & 15, q = j >> 4;
    const int n = blockIdx.x * 4 + w;
    if (j == 0) snll[w] = 0.f;
    if (n < N) {
        const int rlen = deg[n];
        const int row = locx[n] + bsum[n >> 8];
        const float ad = a_d[n];
        float4 acc = {0.f, 0.f, 0.f, 0.f};
        float den = 0.f;
        for (int base = 0; base < rlen; base += 64) {
            int m = rlen - base; if (m > 64) m = 64;
            int myS = 0; float ex = 0.f;
            if (j < m) {
                myS = srcs[row + base + j];
                float v = a_s[myS] + ad;
                v = v > 0.f ? v : NEG * v;
                ex = expf(v);
            }
            float ds = ex;
            #pragma unroll
            for (int off = 1; off < 64; off <<= 1) ds += __shfl_xor(ds, off);
            den += ds;
            int eb = 0;
            for (; eb + 16 <= m; eb += 16) {           // 4 gathers in flight
                int s4[4]; float e4[4]; float4 l4[4];
                #pragma unroll
                for (int ii = 0; ii < 4; ++ii) {
                    int e = eb + 4 * ii + q;
                    s4[ii] = __shfl(myS, e);
                    e4[ii] = __shfl(ex, e);
                }
                #pragma unroll
                for (int ii = 0; ii < 4; ++ii)
                    l4[ii] = *(const float4*)&h2[(size_t)s4[ii] * 64 + 4 * t];
                #pragma unroll
                for (int ii = 0; ii < 4; ++ii)
                    fma4(acc, e4[ii], l4[ii]);
            }
            for (; eb + 4 <= m; eb += 4) {
                int e = eb + q;
                int sk = __shfl(myS, e);
                float ek = __shfl(ex, e);
                float4 lk = *(const float4*)&h2[(size_t)sk * 64 + 4 * t];
                fma4(acc, ek, lk);
            }
            for (int k = eb; k < m; ++k) {
                int sk = __shfl(myS, k);
                float ek = __shfl(ex, k);
                if (q == (k & 3)) {
                    float4 lk = *(const float4*)&h2[(size_t)sk * 64 + 4 * t];
                    fma4(acc, ek, lk);
                }
            }
        }
        acc.x += __shfl_xor(acc.x, 16); acc.y += __shfl_xor(acc.y, 16);
        acc.z += __shfl_xor(acc.z, 16); acc.w += __shfl_xor(acc.w, 16);
        acc.x += __shfl_xor(acc.x, 32); acc.y += __shfl_xor(acc.y, 32);
        acc.z += __shfl_xor(acc.z, 32); acc.w += __shfl_xor(acc.w, 32);
        float4 b = *(const float4*)&b2[4 * t];
        float4 sc;
        sc.x = acc.x / den + b.x; sc.y = acc.y / den + b.y;
        sc.z = acc.z / den + b.z; sc.w = acc.w / den + b.w;
        float mv = sc.x; int mi = 4 * t;
        if (sc.y > mv) { mv = sc.y; mi = 4 * t + 1; }
        if (sc.z > mv) { mv = sc.z; mi = 4 * t + 2; }
        if (sc.w > mv) { mv = sc.w; mi = 4 * t + 3; }
        #pragma unroll
        for (int off = 1; off < 16; off <<= 1) {
            float ov = __shfl_xor(mv, off);
            int oi = __shfl_xor(mi, off);
            if (ov > mv || (ov == mv && oi < mi)) { mv = ov; mi = oi; }
        }
        float se = expf(sc.x - mv) + expf(sc.y - mv) + expf(sc.z - mv) + expf(sc.w - mv);
        #pragma unroll
        for (int off = 1; off < 16; off <<= 1) se += __shfl_xor(se, off);
        int lab = label[n];
        int comp = lab & 3;
        float cl = comp == 0 ? sc.x : comp == 1 ? sc.y : comp == 2 ? sc.z : sc.w;
        float sl = __shfl(cl, (j & 0x30) | (lab >> 2));
        if (j == 0) {
            snll[w] = mv + logf(se) - sl;
            dout[1 + n] = (float)mi;
            dout[1 + (size_t)N + n] = (float)lab;
        }
    }
    __syncthreads();
    if (tid == 0) {
        double bsum4 = (double)snll[0] + (double)snll[1]
                     + (double)snll[2] + (double)snll[3];
        atomicAdd(&bins[blockIdx.x & (NBINS - 1)], bsum4);
    }
}

// Single block of 256: reduce NBINS doubles -> loss
__global__ __launch_bounds__(256) void k_loss(
    const double* __restrict__ bins, float* __restrict__ dout, int N)
{
    __shared__ double sw[4];
    const int tid = threadIdx.x;
    double v = bins[tid];
    #pragma unroll
    for (int off = 1; off < 64; off <<= 1) v += __shfl_xor(v, off);
    if ((tid & 63) == 0) sw[tid >> 6] = v;
    __syncthreads();
    if (tid == 0)
        dout[0] = (float)((sw[0] + sw[1] + sw[2] + sw[3]) / (double)N);
}

extern "C" void kernel_launch(void* const* d_in, const int* in_sizes, int n_in,
                              void* d_out, int out_size, void* d_ws, size_t ws_size,
                              hipStream_t stream)
{
    const float* feat   = (const float*)d_in[1];
    const int*   edge   = (const int*)d_in[2];
    const int*   label  = (const int*)d_in[4];
    const float* W1     = (const float*)d_in[5];
    const float* att_s1 = (const float*)d_in[6];
    const float* att_d1 = (const float*)d_in[7];
    const float* b1     = (const float*)d_in[8];
    const float* W2     = (const float*)d_in[9];
    const float* att_s2 = (const float*)d_in[10];
    const float* att_d2 = (const float*)d_in[11];
    const float* b2     = (const float*)d_in[12];

    const int N = in_sizes[0];
    const int E = in_sizes[2] / 2;
    const int* src = edge;
    const int* dst = edge + E;

    // workspace layout:
    float* bufA = (float*)d_ws;               // N*64: h1 / h2 (no aliases)
    float* bufB = bufA + (size_t)N * 64;      // N*64: x; aliases rank[E]+deg8[8N]+base8[8N]
    float* a_s1 = bufB + (size_t)N * 64;      // N*8 (layer2: a_s2=[0..N), a_d2=[N..2N))
    float* a_d1 = a_s1 + (size_t)N * 8;       // N*8
    int*   deg  = (int*)(a_d1 + (size_t)N * 8); // N
    int*   locx = deg + N;                    // N
    int*   srcs = locx + N;                   // E
    int*   bsum = srcs + E;                   // nblk (scan scratch)
    double* bins = (double*)(((uintptr_t)(bsum + ((N + 255) / 256) + 1) + 7) & ~(uintptr_t)7);

    // Aliases in bufB — all dead before k_agg1 writes x:
    // rank[E], deg8[8N], base8[8N]: E+16N ints = ~13 MB < 25.6 MB. E <= 64N req'd.
    int* rank  = (int*)bufB;                  // E
    int* deg8  = rank + E;                    // 8N
    int* base8 = deg8 + (size_t)8 * N;        // 8N

    float* a_s2 = a_s1;
    float* a_d2 = a_s1 + N;

    float* out = (float*)d_out;

    const int nblk  = (N + 255) / 256;
    const int egrid = (E + 255) / 256;
    const int G1    = (N + 63) / 64;

    hipMemsetAsync(deg8, 0, (size_t)8 * N * sizeof(int), stream);

    // gemm1 overlapped with histogram (independent); then scans; then fill.
    k_gemm1_hist<<<G1 + egrid, 256, 0, stream>>>(feat, W1, att_s1, att_d1,
                                                 bufA, a_s1, a_d1,
                                                 dst, deg8, rank, N, E, G1);
    k_scan1r<<<nblk, 256, 0, stream>>>(deg8, base8, deg, locx, bsum, bins, N);
    k_scan2 <<<1, 256, 0, stream>>>(bsum, nblk);
    k_fill  <<<egrid, 256, 0, stream>>>(src, dst, rank, locx, bsum, base8, srcs, E, N);

    k_agg1 <<<(N + 3) / 4, 256, 0, stream>>>(deg, locx, bsum, srcs, a_s1, a_d1,
                                             bufA, b1, bufB, N);
    k_gemm2<<<G1, 256, 0, stream>>>(bufB, W2, att_s2, att_d2, bufA, a_s2, a_d2, N);
    k_agg2 <<<(N + 3) / 4, 256, 0, stream>>>(deg, locx, bsum, srcs, a_s2, a_d2,
                                             bufA, b2, label, out, bins, N);
    k_loss <<<1, 256, 0, stream>>>(bins, out, N);
}

// Round 13
// 507.797 us; speedup vs baseline: 1.0436x; 1.0048x over previous
//
#include <hip/hip_runtime.h>
#include <cstdint>

#define NHEAD 8
#define D1 64      // H1*C1
#define IN_F 128
#define NEG 0.2f
#define NBINS 256  // loss partial-sum bins

__device__ __forceinline__ void fma4(float4& a, float s, const float4& v)
{
    a.x = fmaf(s, v.x, a.x); a.y = fmaf(s, v.y, a.y);
    a.z = fmaf(s, v.z, a.z); a.w = fmaf(s, v.w, a.w);
}

// ---------------- Fused: gemm1 (h1 = feat@W1 + att dots) & hist8 ----------------
// Round-12 lesson: partition index MUST track the XCD (p = global blockIdx & 7).
// The fused kernel's p=(blockIdx-G1)&7 was offset by G1&7=3 from the XCD id ->
// 7/8 of deg8 atomics went cross-XCD -> 54 MB of L2 line write-backs (WRITE_SIZE
// 88 MB vs 34 MB legit) and a latency-bound 125 us kernel.
__global__ __launch_bounds__(256) void k_gemm1_hist(
    const float* __restrict__ feat,
    const float* __restrict__ W1,
    const float* __restrict__ att_s,
    const float* __restrict__ att_d,
    float* __restrict__ h1, float* __restrict__ a_src, float* __restrict__ a_dst,
    const int* __restrict__ dst, int* __restrict__ deg8, int* __restrict__ rank,
    int N, int E, int G1)
{
    __shared__ float Wh[64 * 64];   // [kk][c], 16 KB
    __shared__ float Fh[64 * 68];   // [r][kk], stride 68, 17.4 KB
    const int tid = threadIdx.x;

    if ((int)blockIdx.x >= G1) {
        // -------- histogram branch; p = GLOBAL blockIdx & 7 (~XCD id) ----------
        int e = (blockIdx.x - G1) * 256 + tid;
        if (e < E) {
            int p = blockIdx.x & 7;
            rank[e] = atomicAdd(&deg8[p * N + dst[e]], 1);  // rank write coalesced
        }
        return;
    }

    // -------- gemm1 branch: 64x64 tile, 4x4 register tile, K in two halves -----
    const int tx = tid & 15, ty = tid >> 4;
    const int base = blockIdx.x * 64;
    float4 acc0 = {0,0,0,0}, acc1 = {0,0,0,0}, acc2 = {0,0,0,0}, acc3 = {0,0,0,0};

    for (int p = 0; p < 2; ++p) {
        if (p) __syncthreads();
        for (int i = tid; i < 64 * 64; i += 256)
            Wh[i] = W1[p * 4096 + i];
        for (int i = tid; i < 64 * 64; i += 256) {
            int r = i >> 6, kk = i & 63;
            int n = base + r;
            Fh[r * 68 + kk] = (n < N) ? feat[(size_t)n * IN_F + p * 64 + kk] : 0.f;
        }
        __syncthreads();
        const float* wk = &Wh[4 * tx];
        const float* f0 = &Fh[(4 * ty + 0) * 68];
        const float* f1 = &Fh[(4 * ty + 1) * 68];
        const float* f2 = &Fh[(4 * ty + 2) * 68];
        const float* f3 = &Fh[(4 * ty + 3) * 68];
        #pragma unroll 4
        for (int kk = 0; kk < 64; kk += 4) {
            float4 fa = *(const float4*)&f0[kk];
            float4 fb = *(const float4*)&f1[kk];
            float4 fc = *(const float4*)&f2[kk];
            float4 fd = *(const float4*)&f3[kk];
            float4 w0 = *(const float4*)&wk[(kk + 0) * 64];
            float4 w1 = *(const float4*)&wk[(kk + 1) * 64];
            float4 w2 = *(const float4*)&wk[(kk + 2) * 64];
            float4 w3 = *(const float4*)&wk[(kk + 3) * 64];
            fma4(acc0, fa.x, w0); fma4(acc0, fa.y, w1); fma4(acc0, fa.z, w2); fma4(acc0, fa.w, w3);
            fma4(acc1, fb.x, w0); fma4(acc1, fb.y, w1); fma4(acc1, fb.z, w2); fma4(acc1, fb.w, w3);
            fma4(acc2, fc.x, w0); fma4(acc2, fc.y, w1); fma4(acc2, fc.z, w2); fma4(acc2, fc.w, w3);
            fma4(acc3, fd.x, w0); fma4(acc3, fd.y, w1); fma4(acc3, fd.z, w2); fma4(acc3, fd.w, w3);
        }
    }
    const float4 as4 = *(const float4*)&att_s[4 * tx];
    const float4 ad4 = *(const float4*)&att_d[4 * tx];
    float4 accs[4] = {acc0, acc1, acc2, acc3};
    #pragma unroll
    for (int i = 0; i < 4; ++i) {
        int n = base + 4 * ty + i;
        if (n < N) {
            *(float4*)&h1[(size_t)n * D1 + 4 * tx] = accs[i];
            float ps = accs[i].x * as4.x + accs[i].y * as4.y + accs[i].z * as4.z + accs[i].w * as4.w;
            float pd = accs[i].x * ad4.x + accs[i].y * ad4.y + accs[i].z * ad4.z + accs[i].w * ad4.w;
            ps += __shfl_xor(ps, 1);
            pd += __shfl_xor(pd, 1);
            if ((tx & 1) == 0) {
                a_src[n * NHEAD + (tx >> 1)] = ps;
                a_dst[n * NHEAD + (tx >> 1)] = pd;
            }
        }
    }
}

__device__ __forceinline__ int block_incl_scan(int v, int tid, int* lds4)
{
    int lane = tid & 63, w = tid >> 6;
    #pragma unroll
    for (int off = 1; off < 64; off <<= 1) {
        int t = __shfl_up(v, off);
        if (lane >= off) v += t;
    }
    if (lane == 63) lds4[w] = v;
    __syncthreads();
    int add = 0;
    #pragma unroll
    for (int i = 0; i < 4; ++i)
        if (i < w) add += lds4[i];
    __syncthreads();
    return v + add;
}

// scan1 with reduce8 folded in: deg = sum_p deg8, base8 = per-p exclusive bases.
__global__ __launch_bounds__(256) void k_scan1r(
    const int* __restrict__ deg8, int* __restrict__ base8, int* __restrict__ deg,
    int* __restrict__ locx, int* __restrict__ bsum, double* __restrict__ bins, int N)
{
    __shared__ int lds4[4];
    if (blockIdx.x == 0) bins[threadIdx.x] = 0.0;   // fold bins zeroing here
    int i = blockIdx.x * 256 + threadIdx.x;
    int v = 0;
    if (i < N) {
        int b = 0;
        #pragma unroll
        for (int p = 0; p < 8; ++p) {
            base8[p * N + i] = b;
            b += deg8[p * N + i];
        }
        deg[i] = b;
        v = b;
    }
    int incl = block_incl_scan(v, threadIdx.x, lds4);
    if (i < N) locx[i] = incl - v;
    if (threadIdx.x == 255) bsum[blockIdx.x] = incl;
}

__global__ __launch_bounds__(256) void k_scan2(int* __restrict__ bsum, int nblk)
{
    __shared__ int lds4[4];
    __shared__ int carry;
    if (threadIdx.x == 0) carry = 0;
    __syncthreads();
    for (int base = 0; base < nblk; base += 256) {
        int i = base + threadIdx.x;
        int v = (i < nblk) ? bsum[i] : 0;
        int incl = block_incl_scan(v, threadIdx.x, lds4);
        int c = carry;
        __syncthreads();
        if (i < nblk) bsum[i] = incl - v + c;
        if (threadIdx.x == 255) carry = c + incl;
        __syncthreads();
    }
}

// offs computed inline: locx[d] + bsum[d>>8].
// atomicExch: plain scattered 4B stores write through at 64B/op; exch stays in L2.
// p must reproduce the hist branch's mapping: hist block for e = G1 + (e>>8).
__global__ __launch_bounds__(256) void k_fill(
    const int* __restrict__ src, const int* __restrict__ dst,
    const int* __restrict__ rank, const int* __restrict__ locx,
    const int* __restrict__ bsum, const int* __restrict__ base8,
    int* __restrict__ srcs, int E, int N, int G1)
{
    int e = blockIdx.x * 256 + threadIdx.x;
    if (e < E) {
        int p = (blockIdx.x + G1) & 7;    // == hist's (G1 + (e>>8)) & 7
        int d = dst[e];
        int slot = locx[d] + bsum[d >> 8] + base8[p * N + d] + rank[e];
        (void)atomicExch(&srcs[slot], src[e]);
    }
}

// ---------------- Layer-1 aggregation, 2-deep software pipeline ----------------
__global__ __launch_bounds__(256) void k_agg1(
    const int* __restrict__ deg, const int* __restrict__ locx,
    const int* __restrict__ bsum, const int* __restrict__ srcs,
    const float* __restrict__ a_s, const float* __restrict__ a_d,
    const float* __restrict__ h1, const float* __restrict__ b1,
    float* __restrict__ x, int N)
{
    const int tid = threadIdx.x, w = tid >> 6, j = tid & 63;
    const int c = j & 7, hh = j >> 3;      // producer: edge-slot c, head hh
    const int n = blockIdx.x * 4 + w;
    if (n >= N) return;
    const int rlen = deg[n];
    const int row = locx[n] + bsum[n >> 8];
    const float ad = a_d[n * NHEAD + hh];
    float acc0 = 0.f, acc1 = 0.f, den = 0.f;
    int m = rlen < 8 ? rlen : 8;
    int myS   = (c < m) ? srcs[row + c] : 0;
    float av  = (c < m) ? a_s[myS * NHEAD + hh] : 0.f;
    for (int base = 0; base < rlen; base += 8) {
        int mn = rlen - base - 8; if (mn > 8) mn = 8;
        int   myS_n = (c < mn) ? srcs[row + base + 8 + c] : 0;
        float av_n  = (c < mn) ? a_s[myS_n * NHEAD + hh] : 0.f;
        float ex = 0.f;
        if (c < m) {
            float v = av + ad;
            v = v > 0.f ? v : NEG * v;
            ex = expf(v);
        }
        float ds = ex;                      // per-head denom: aligned 8-lane group reduce
        ds += __shfl_xor(ds, 1);
        ds += __shfl_xor(ds, 2);
        ds += __shfl_xor(ds, 4);
        den += ds;
        if (m == 8) {
            int   s8[8]; float e8[8], l8[8];
            #pragma unroll
            for (int k = 0; k < 8; ++k) {
                s8[k] = __builtin_amdgcn_readlane(myS, k);
                e8[k] = __shfl(ex, (j & 0x38) | k);
            }
            #pragma unroll
            for (int k = 0; k < 8; ++k)
                l8[k] = h1[(size_t)s8[k] * D1 + j];   // 8 loads in flight
            #pragma unroll
            for (int k = 0; k < 8; ++k) {
                if (k & 1) acc1 = fmaf(e8[k], l8[k], acc1);
                else       acc0 = fmaf(e8[k], l8[k], acc0);
            }
        } else {
            for (int k = 0; k < m; ++k) {
                int s = __shfl(myS, k);
                float exk = __shfl(ex, (j & 0x38) | k);
                if (k & 1) acc1 = fmaf(exk, h1[(size_t)s * D1 + j], acc1);
                else       acc0 = fmaf(exk, h1[(size_t)s * D1 + j], acc0);
            }
        }
        myS = myS_n; av = av_n; m = mn > 0 ? mn : 0;
    }
    float o = (acc0 + acc1) / den + b1[j];
    x[(size_t)n * D1 + j] = o > 0.f ? o : expm1f(o);
}

// ---------------- Kernel D: h2 = x @ W2, a_src2/a_dst2 (4x4 register tile) ----------------
__global__ __launch_bounds__(256) void k_gemm2(
    const float* __restrict__ x,
    const float* __restrict__ W2,
    const float* __restrict__ att_s,
    const float* __restrict__ att_d,
    float* __restrict__ h2, float* __restrict__ a_src, float* __restrict__ a_dst,
    int N)
{
    __shared__ float Wh[64 * 64];
    __shared__ float Fh[64 * 68];
    const int tid = threadIdx.x;
    const int tx = tid & 15, ty = tid >> 4;
    const int base = blockIdx.x * 64;
    for (int i = tid; i < 64 * 64; i += 256)
        Wh[i] = W2[i];
    for (int i = tid; i < 64 * 64; i += 256) {
        int r = i >> 6, kk = i & 63;
        int n = base + r;
        Fh[r * 68 + kk] = (n < N) ? x[(size_t)n * 64 + kk] : 0.f;
    }
    __syncthreads();
    float4 acc0 = {0,0,0,0}, acc1 = {0,0,0,0}, acc2 = {0,0,0,0}, acc3 = {0,0,0,0};
    const float* wk = &Wh[4 * tx];
    const float* f0 = &Fh[(4 * ty + 0) * 68];
    const float* f1 = &Fh[(4 * ty + 1) * 68];
    const float* f2 = &Fh[(4 * ty + 2) * 68];
    const float* f3 = &Fh[(4 * ty + 3) * 68];
    #pragma unroll 4
    for (int kk = 0; kk < 64; kk += 4) {
        float4 fa = *(const float4*)&f0[kk];
        float4 fb = *(const float4*)&f1[kk];
        float4 fc = *(const float4*)&f2[kk];
        float4 fd = *(const float4*)&f3[kk];
        float4 w0 = *(const float4*)&wk[(kk + 0) * 64];
        float4 w1 = *(const float4*)&wk[(kk + 1) * 64];
        float4 w2 = *(const float4*)&wk[(kk + 2) * 64];
        float4 w3 = *(const float4*)&wk[(kk + 3) * 64];
        fma4(acc0, fa.x, w0); fma4(acc0, fa.y, w1); fma4(acc0, fa.z, w2); fma4(acc0, fa.w, w3);
        fma4(acc1, fb.x, w0); fma4(acc1, fb.y, w1); fma4(acc1, fb.z, w2); fma4(acc1, fb.w, w3);
        fma4(acc2, fc.x, w0); fma4(acc2, fc.y, w1); fma4(acc2, fc.z, w2); fma4(acc2, fc.w, w3);
        fma4(acc3, fd.x, w0); fma4(acc3, fd.y, w1); fma4(acc3, fd.z, w2); fma4(acc3, fd.w, w3);
    }
    const float4 as4 = *(const float4*)&att_s[4 * tx];
    const float4 ad4 = *(const float4*)&att_d[4 * tx];
    float4 accs[4] = {acc0, acc1, acc2, acc3};
    #pragma unroll
    for (int i = 0; i < 4; ++i) {
        int n = base + 4 * ty + i;
        if (n < N) {
            *(float4*)&h2[(size_t)n * 64 + 4 * tx] = accs[i];
            float ps = accs[i].x * as4.x + accs[i].y * as4.y + accs[i].z * as4.z + accs[i].w * as4.w;
            float pd = accs[i].x * ad4.x + accs[i].y * ad4.y + accs[i].z * ad4.z + accs[i].w * ad4.w;
            ps += __shfl_xor(ps, 1); pd += __shfl_xor(pd, 1);
            ps += __shfl_xor(ps, 2); pd += __shfl_xor(pd, 2);
            ps += __shfl_xor(ps, 4); pd += __shfl_xor(pd, 4);
            ps += __shfl_xor(ps, 8); pd += __shfl_xor(pd, 8);
            if (tx == 0) { a_src[n] = ps; a_dst[n] = pd; }
        }
    }
}

// ---------------- Layer-2 aggregation + bias + log-softmax + argmax + NLL ----------------
__global__ __launch_bounds__(256) void k_agg2(
    const int* __restrict__ deg, const int* __restrict__ locx,
    const int* __restrict__ bsum, const int* __restrict__ srcs,
    const float* __restrict__ a_s, const float* __restrict__ a_d,
    const float* __restrict__ h2, const float* __restrict__ b2,
    const int* __restrict__ label,
    float* __restrict__ dout, double* __restrict__ bins, int N)
{
    __shared__ float snll[4];
    const int tid = threadIdx.x, w = tid >> 6, j = tid & 63;
    const int t = j & 15, q = j >> 4;
    const int n = blockIdx.x * 4 + w;
    if (j == 0) snll[w] = 0.f;
    if (n < N) {
        const int rlen = deg[n];
        const int row = locx[n] + bsum[n >> 8];
        const float ad = a_d[n];
        float4 acc = {0.f, 0.f, 0.f, 0.f};
        float den = 0.f;
        for (int base = 0; base < rlen; base += 64) {
            int m = rlen - base; if (m > 64) m = 64;
            int myS = 0; float ex = 0.f;
            if (j < m) {
                myS = srcs[row + base + j];
                float v = a_s[myS] + ad;
                v = v > 0.f ? v : NEG * v;
                ex = expf(v);
            }
            float ds = ex;
            #pragma unroll
            for (int off = 1; off < 64; off <<= 1) ds += __shfl_xor(ds, off);
            den += ds;
            int eb = 0;
            for (; eb + 16 <= m; eb += 16) {           // 4 gathers in flight
                int s4[4]; float e4[4]; float4 l4[4];
                #pragma unroll
                for (int ii = 0; ii < 4; ++ii) {
                    int e = eb + 4 * ii + q;
                    s4[ii] = __shfl(myS, e);
                    e4[ii] = __shfl(ex, e);
                }
                #pragma unroll
                for (int ii = 0; ii < 4; ++ii)
                    l4[ii] = *(const float4*)&h2[(size_t)s4[ii] * 64 + 4 * t];
                #pragma unroll
                for (int ii = 0; ii < 4; ++ii)
                    fma4(acc, e4[ii], l4[ii]);
            }
            for (; eb + 4 <= m; eb += 4) {
                int e = eb + q;
                int sk = __shfl(myS, e);
                float ek = __shfl(ex, e);
                float4 lk = *(const float4*)&h2[(size_t)sk * 64 + 4 * t];
                fma4(acc, ek, lk);
            }
            for (int k = eb; k < m; ++k) {
                int sk = __shfl(myS, k);
                float ek = __shfl(ex, k);
                if (q == (k & 3)) {
                    float4 lk = *(const float4*)&h2[(size_t)sk * 64 + 4 * t];
                    fma4(acc, ek, lk);
                }
            }
        }
        acc.x += __shfl_xor(acc.x, 16); acc.y += __shfl_xor(acc.y, 16);
        acc.z += __shfl_xor(acc.z, 16); acc.w += __shfl_xor(acc.w, 16);
        acc.x += __shfl_xor(acc.x, 32); acc.y += __shfl_xor(acc.y, 32);
        acc.z += __shfl_xor(acc.z, 32); acc.w += __shfl_xor(acc.w, 32);
        float4 b = *(const float4*)&b2[4 * t];
        float4 sc;
        sc.x = acc.x / den + b.x; sc.y = acc.y / den + b.y;
        sc.z = acc.z / den + b.z; sc.w = acc.w / den + b.w;
        float mv = sc.x; int mi = 4 * t;
        if (sc.y > mv) { mv = sc.y; mi = 4 * t + 1; }
        if (sc.z > mv) { mv = sc.z; mi = 4 * t + 2; }
        if (sc.w > mv) { mv = sc.w; mi = 4 * t + 3; }
        #pragma unroll
        for (int off = 1; off < 16; off <<= 1) {
            float ov = __shfl_xor(mv, off);
            int oi = __shfl_xor(mi, off);
            if (ov > mv || (ov == mv && oi < mi)) { mv = ov; mi = oi; }
        }
        float se = expf(sc.x - mv) + expf(sc.y - mv) + expf(sc.z - mv) + expf(sc.w - mv);
        #pragma unroll
        for (int off = 1; off < 16; off <<= 1) se += __shfl_xor(se, off);
        int lab = label[n];
        int comp = lab & 3;
        float cl = comp == 0 ? sc.x : comp == 1 ? sc.y : comp == 2 ? sc.z : sc.w;
        float sl = __shfl(cl, (j & 0x30) | (lab >> 2));
        if (j == 0) {
            snll[w] = mv + logf(se) - sl;
            dout[1 + n] = (float)mi;
            dout[1 + (size_t)N + n] = (float)lab;
        }
    }
    __syncthreads();
    if (tid == 0) {
        double bsum4 = (double)snll[0] + (double)snll[1]
                     + (double)snll[2] + (double)snll[3];
        atomicAdd(&bins[blockIdx.x & (NBINS - 1)], bsum4);
    }
}

// Single block of 256: reduce NBINS doubles -> loss
__global__ __launch_bounds__(256) void k_loss(
    const double* __restrict__ bins, float* __restrict__ dout, int N)
{
    __shared__ double sw[4];
    const int tid = threadIdx.x;
    double v = bins[tid];
    #pragma unroll
    for (int off = 1; off < 64; off <<= 1) v += __shfl_xor(v, off);
    if ((tid & 63) == 0) sw[tid >> 6] = v;
    __syncthreads();
    if (tid == 0)
        dout[0] = (float)((sw[0] + sw[1] + sw[2] + sw[3]) / (double)N);
}

extern "C" void kernel_launch(void* const* d_in, const int* in_sizes, int n_in,
                              void* d_out, int out_size, void* d_ws, size_t ws_size,
                              hipStream_t stream)
{
    const float* feat   = (const float*)d_in[1];
    const int*   edge   = (const int*)d_in[2];
    const int*   label  = (const int*)d_in[4];
    const float* W1     = (const float*)d_in[5];
    const float* att_s1 = (const float*)d_in[6];
    const float* att_d1 = (const float*)d_in[7];
    const float* b1     = (const float*)d_in[8];
    const float* W2     = (const float*)d_in[9];
    const float* att_s2 = (const float*)d_in[10];
    const float* att_d2 = (const float*)d_in[11];
    const float* b2     = (const float*)d_in[12];

    const int N = in_sizes[0];
    const int E = in_sizes[2] / 2;
    const int* src = edge;
    const int* dst = edge + E;

    // workspace layout:
    float* bufA = (float*)d_ws;               // N*64: h1 / h2 (no aliases)
    float* bufB = bufA + (size_t)N * 64;      // N*64: x; aliases rank[E]+deg8[8N]+base8[8N]
    float* a_s1 = bufB + (size_t)N * 64;      // N*8 (layer2: a_s2=[0..N), a_d2=[N..2N))
    float* a_d1 = a_s1 + (size_t)N * 8;       // N*8
    int*   deg  = (int*)(a_d1 + (size_t)N * 8); // N
    int*   locx = deg + N;                    // N
    int*   srcs = locx + N;                   // E
    int*   bsum = srcs + E;                   // nblk (scan scratch)
    double* bins = (double*)(((uintptr_t)(bsum + ((N + 255) / 256) + 1) + 7) & ~(uintptr_t)7);

    // Aliases in bufB — all dead before k_agg1 writes x:
    int* rank  = (int*)bufB;                  // E
    int* deg8  = rank + E;                    // 8N
    int* base8 = deg8 + (size_t)8 * N;        // 8N

    float* a_s2 = a_s1;
    float* a_d2 = a_s1 + N;

    float* out = (float*)d_out;

    const int nblk  = (N + 255) / 256;
    const int egrid = (E + 255) / 256;
    const int G1    = (N + 63) / 64;

    hipMemsetAsync(deg8, 0, (size_t)8 * N * sizeof(int), stream);

    // gemm1 overlapped with histogram (independent); then scans; then fill.
    k_gemm1_hist<<<G1 + egrid, 256, 0, stream>>>(feat, W1, att_s1, att_d1,
                                                 bufA, a_s1, a_d1,
                                                 dst, deg8, rank, N, E, G1);
    k_scan1r<<<nblk, 256, 0, stream>>>(deg8, base8, deg, locx, bsum, bins, N);
    k_scan2 <<<1, 256, 0, stream>>>(bsum, nblk);
    k_fill  <<<egrid, 256, 0, stream>>>(src, dst, rank, locx, bsum, base8, srcs, E, N, G1);

    k_agg1 <<<(N + 3) / 4, 256, 0, stream>>>(deg, locx, bsum, srcs, a_s1, a_d1,
                                             bufA, b1, bufB, N);
    k_gemm2<<<G1, 256, 0, stream>>>(bufB, W2, att_s2, att_d2, bufA, a_s2, a_d2, N);
    k_agg2 <<<(N + 3) / 4, 256, 0, stream>>>(deg, locx, bsum, srcs, a_s2, a_d2,
                                             bufA, b2, label, out, bins, N);
    k_loss <<<1, 256, 0, stream>>>(bins, out, N);
}